// Round 1
// baseline (491.363 us; speedup 1.0000x reference)
//
#include <hip/hip_runtime.h>
#include <math.h>

#define B_   32
#define M_   32
#define P_   196
#define D_   20
#define O_   16
#define I_   8
#define DO_  320   // D*O
#define PD_  3920  // P*D
#define TP_  14    // p-tile per block
#define NPT_ 14    // P / TP

// ws layout (floats):
//   blog : [B][M][P][D]            @ 0        (4,014,080)
//   part : [M*NPT][B][DO]          @ 4014080  (4,587,520)
//   vbuf : [B][DO]                 @ 8601600  (10,240)
//   mx   : [B*M]                   @ 8611840  (1,024)
//   iz   : [B*M]                   @ 8612864  (1,024)
#define OFF_PART 4014080
#define OFF_V    8601600
#define OFF_MX   8611840
#define OFF_IZ   8612864

#define CMAPS_OFF 10240
#define FEAT_OFF  4024320  // 10240 + 4014080

// PHASE 0: s1 partials (uniform c = 1/PD)
// PHASE 1: blog  = u_hat . v1   (store)
// PHASE 2: s2 partials (c from blog+mx/iz)
// PHASE 3: blog += u_hat . v2   (rmw)
// PHASE 4: s3 partials + c_maps (c from blog+mx/iz)
template<int PHASE>
__global__ __launch_bounds__(256)
void caps_pass(const float* __restrict__ x, const float* __restrict__ W,
               float* __restrict__ blog, const float* __restrict__ mx,
               const float* __restrict__ iz, const float* __restrict__ vin,
               float* __restrict__ part, float* __restrict__ out)
{
    extern __shared__ float smem[];
    float* x_lds = smem;                 // [TP][B][I]  3584 fl
    float* c_lds = smem + TP_*B_*I_;     // [TP][B][D]  8960 fl (PHASE 2,4 only)

    const int m   = blockIdx.x / NPT_;
    const int pt  = blockIdx.x % NPT_;
    const int p0  = pt * TP_;
    const int t   = threadIdx.x;
    const int bq  = t >> 5;      // 0..7 -> b = bq*4 + bb
    const int doq = t & 31;      // do = doq + 32*j
    const int hi  = doq >> 4;    // d = 2*j + hi
    const int o   = doq & 15;

    // stage x tile: x_lds[p][b][i]
    for (int f = t; f < TP_*B_*2; f += 256) {
        int b = f / (TP_*2); int r = f - b*(TP_*2); int p = r >> 1; int h = r & 1;
        float4 v4 = *(const float4*)(x + (((size_t)b*M_ + m)*P_ + p0 + p)*I_ + h*4);
        *(float4*)(x_lds + (p*B_ + b)*I_ + h*4) = v4;
    }
    // stage c tile (softmax applied on the fly): c_lds[p][b][d]
    if (PHASE==2 || PHASE==4) {
        for (int e = t; e < TP_*B_*D_; e += 256) {
            int p = e / (B_*D_); int r = e - p*(B_*D_); int b = r / D_; int d = r - b*D_;
            float lv = blog[(((size_t)b*M_ + m)*P_ + p0 + p)*D_ + d];
            c_lds[(p*B_ + b)*D_ + d] = __expf(lv - mx[b*M_+m]) * iz[b*M_+m];
        }
    }
    // v values for agreement phases (each thread's 4b x 10do slots)
    float vv[4][10];
    if (PHASE==1 || PHASE==3) {
        #pragma unroll
        for (int bb = 0; bb < 4; bb++)
            #pragma unroll
            for (int j = 0; j < 10; j++)
                vv[bb][j] = vin[(bq*4+bb)*DO_ + doq + 32*j];
    }
    float acc[4][10];
    if (PHASE==0 || PHASE==2 || PHASE==4) {
        #pragma unroll
        for (int bb = 0; bb < 4; bb++)
            #pragma unroll
            for (int j = 0; j < 10; j++) acc[bb][j] = 0.f;
    }
    __syncthreads();

    for (int pl = 0; pl < TP_; pl++) {
        const float* wp = W + (size_t)(m*P_ + p0 + pl)*DO_*I_;
        float xr[4][8];
        #pragma unroll
        for (int bb = 0; bb < 4; bb++) {
            float4 a0 = *(const float4*)(x_lds + (pl*B_ + bq*4+bb)*I_);
            float4 a1 = *(const float4*)(x_lds + (pl*B_ + bq*4+bb)*I_ + 4);
            xr[bb][0]=a0.x; xr[bb][1]=a0.y; xr[bb][2]=a0.z; xr[bb][3]=a0.w;
            xr[bb][4]=a1.x; xr[bb][5]=a1.y; xr[bb][6]=a1.z; xr[bb][7]=a1.w;
        }
        #pragma unroll
        for (int j = 0; j < 10; j++) {
            const int dd = 2*j + hi;
            const float4* w4 = (const float4*)(wp + (doq + 32*j)*I_);
            float4 w0 = w4[0], w1 = w4[1];
            float u[4];
            #pragma unroll
            for (int bb = 0; bb < 4; bb++) {
                float s = w0.x * xr[bb][0];
                s = fmaf(w0.y, xr[bb][1], s);
                s = fmaf(w0.z, xr[bb][2], s);
                s = fmaf(w0.w, xr[bb][3], s);
                s = fmaf(w1.x, xr[bb][4], s);
                s = fmaf(w1.y, xr[bb][5], s);
                s = fmaf(w1.z, xr[bb][6], s);
                s = fmaf(w1.w, xr[bb][7], s);
                u[bb] = s;
            }
            if (PHASE==0) {
                #pragma unroll
                for (int bb = 0; bb < 4; bb++) acc[bb][j] += u[bb];
            }
            if (PHASE==2 || PHASE==4) {
                #pragma unroll
                for (int bb = 0; bb < 4; bb++) {
                    float cv = c_lds[(pl*B_ + bq*4+bb)*D_ + dd];
                    acc[bb][j] = fmaf(cv, u[bb], acc[bb][j]);
                }
            }
            if (PHASE==1 || PHASE==3) {
                float r[4];
                #pragma unroll
                for (int bb = 0; bb < 4; bb++) r[bb] = u[bb] * vv[bb][j];
                #pragma unroll
                for (int msk = 1; msk < 16; msk <<= 1) {
                    #pragma unroll
                    for (int bb = 0; bb < 4; bb++) r[bb] += __shfl_xor(r[bb], msk, 64);
                }
                if (o == 0) {
                    #pragma unroll
                    for (int bb = 0; bb < 4; bb++) {
                        size_t a = (((size_t)(bq*4+bb)*M_ + m)*P_ + p0 + pl)*D_ + dd;
                        if (PHASE==1) blog[a] = r[bb];
                        else          blog[a] += r[bb];
                    }
                }
            }
            if (PHASE==4) {
                float q[4];
                #pragma unroll
                for (int bb = 0; bb < 4; bb++) q[bb] = u[bb] * u[bb];
                #pragma unroll
                for (int msk = 1; msk < 16; msk <<= 1) {
                    #pragma unroll
                    for (int bb = 0; bb < 4; bb++) q[bb] += __shfl_xor(q[bb], msk, 64);
                }
                if (o == 0) {
                    #pragma unroll
                    for (int bb = 0; bb < 4; bb++) {
                        float cv = c_lds[(pl*B_ + bq*4+bb)*D_ + dd];
                        out[CMAPS_OFF + (((size_t)(bq*4+bb)*M_ + m)*P_ + p0 + pl)*D_ + dd]
                            = cv * sqrtf(q[bb]);
                    }
                }
            }
        }
    }
    if (PHASE==0 || PHASE==2 || PHASE==4) {
        const float scale = (PHASE==0) ? (1.0f/PD_) : 1.0f;
        #pragma unroll
        for (int bb = 0; bb < 4; bb++)
            #pragma unroll
            for (int j = 0; j < 10; j++)
                part[(((size_t)(m*NPT_ + pt))*B_ + bq*4+bb)*DO_ + doq + 32*j]
                    = acc[bb][j] * scale;
    }
}

// per-(b,m) softmax stats: mx = max over P*D logits, iz = 1/sum(exp(l-mx))
__global__ __launch_bounds__(256)
void mz_k(const float* __restrict__ blog, float* __restrict__ mx, float* __restrict__ iz)
{
    __shared__ float red[8];
    const int bm = blockIdx.x;
    const float* row = blog + (size_t)bm * PD_;
    const int t = threadIdx.x;
    float v[16];
    float lm = -3.4e38f;
    #pragma unroll
    for (int k = 0; k < 16; k++) {
        int idx = t + 256*k;
        v[k] = (idx < PD_) ? row[idx] : -3.4e38f;
        lm = fmaxf(lm, v[k]);
    }
    #pragma unroll
    for (int msk = 1; msk < 64; msk <<= 1) lm = fmaxf(lm, __shfl_xor(lm, msk, 64));
    if ((t & 63) == 0) red[t >> 6] = lm;
    __syncthreads();
    lm = fmaxf(fmaxf(red[0], red[1]), fmaxf(red[2], red[3]));
    float se = 0.f;
    #pragma unroll
    for (int k = 0; k < 16; k++) {
        int idx = t + 256*k;
        if (idx < PD_) se += __expf(v[k] - lm);
    }
    #pragma unroll
    for (int msk = 1; msk < 64; msk <<= 1) se += __shfl_xor(se, msk, 64);
    if ((t & 63) == 0) red[4 + (t >> 6)] = se;
    __syncthreads();
    if (t == 0) {
        float Z = red[4] + red[5] + red[6] + red[7];
        mx[bm] = lm;
        iz[bm] = 1.0f / Z;
    }
}

// reduce partials -> s -> v (squash). WHICH 0/1: write vbuf. WHICH 2: write
// v to out[0:10240] and features to out[FEAT_OFF:].
template<int WHICH>
__global__ __launch_bounds__(320)
void sq_k(const float* __restrict__ part, float* __restrict__ vout,
          float* __restrict__ out)
{
    const int b = blockIdx.x;
    const int t = threadIdx.x;   // do = d*16+o
    float s = 0.f;
    if (WHICH < 2) {
        for (int k = 0; k < M_*NPT_; k++)
            s += part[((size_t)k*B_ + b)*DO_ + t];
    } else {
        for (int mi = 0; mi < M_; mi++) {
            float sub = 0.f;
            #pragma unroll
            for (int pt = 0; pt < NPT_; pt++)
                sub += part[(((size_t)(mi*NPT_ + pt))*B_ + b)*DO_ + t];
            out[FEAT_OFF + ((size_t)b*M_ + mi)*DO_ + t] = sub * (1.0f/P_);
            s += sub;
        }
    }
    float sq = s*s;
    #pragma unroll
    for (int msk = 1; msk < 16; msk <<= 1) sq += __shfl_xor(sq, msk, 64);
    float vr = (sq / (1.f + sq)) * s * rsqrtf(sq + 1e-9f);
    if (WHICH < 2) vout[b*DO_ + t] = vr;
    else           out[b*DO_ + t]  = vr;
}

extern "C" void kernel_launch(void* const* d_in, const int* in_sizes, int n_in,
                              void* d_out, int out_size, void* d_ws, size_t ws_size,
                              hipStream_t stream)
{
    const float* x = (const float*)d_in[0];
    const float* W = (const float*)d_in[1];
    float* out  = (float*)d_out;
    float* ws   = (float*)d_ws;
    float* blog = ws;
    float* part = ws + OFF_PART;
    float* vbuf = ws + OFF_V;
    float* mx   = ws + OFF_MX;
    float* iz   = ws + OFF_IZ;

    const int GB = M_ * NPT_;                       // 448 blocks
    const size_t shA = TP_*B_*I_*sizeof(float);           // 14336 B
    const size_t shC = shA + TP_*B_*D_*sizeof(float);     // 50176 B

    // iter 1: uniform c -> s1 -> v1
    caps_pass<0><<<GB, 256, shA, stream>>>(x, W, blog, mx, iz, vbuf, part, out);
    sq_k<0><<<B_, 320, 0, stream>>>(part, vbuf, out);
    // iter 2: b1 = u_hat.v1 ; softmax ; s2 -> v2
    caps_pass<1><<<GB, 256, shA, stream>>>(x, W, blog, mx, iz, vbuf, part, out);
    mz_k<<<B_*M_, 256, 0, stream>>>(blog, mx, iz);
    caps_pass<2><<<GB, 256, shC, stream>>>(x, W, blog, mx, iz, vbuf, part, out);
    sq_k<1><<<B_, 320, 0, stream>>>(part, vbuf, out);
    // iter 3: b2 += u_hat.v2 ; softmax ; s3 + c_maps + feature partials
    caps_pass<3><<<GB, 256, shA, stream>>>(x, W, blog, mx, iz, vbuf, part, out);
    mz_k<<<B_*M_, 256, 0, stream>>>(blog, mx, iz);
    caps_pass<4><<<GB, 256, shC, stream>>>(x, W, blog, mx, iz, vbuf, part, out);
    sq_k<2><<<B_, 320, 0, stream>>>(part, vbuf, out);
}

// Round 2
// 121.494 us; speedup vs baseline: 4.0444x; 4.0444x over previous
//
#include <hip/hip_runtime.h>
#include <math.h>

#define B_   32
#define M_   32
#define P_   196
#define D_   20
#define O_   16
#define I_   8
#define DO_  320    // D*O
#define PD_  3920   // P*D
#define ROW_ 62720  // P*DO

#define CMAPS_OFF 10240
#define FEAT_OFF  4024320

// ws layout (bytes): uh bf16 [B][M][P][DO] @0 (128,450,560 B)
// then floats: pbm [B][M][DO], v1 [B][DO], vs [B][DO]
#define UH_FLOATS 16056320            // 64.2M ushorts = 32,112,640 B... (see host)
// (host computes offsets; kernels take pointers)

__device__ __forceinline__ unsigned short f2bf(float v) {
    unsigned int u = __float_as_uint(v);
    return (unsigned short)((u + 0x7fffu + ((u >> 16) & 1u)) >> 16);
}
__device__ __forceinline__ float bfhi(unsigned int w) { return __uint_as_float(w & 0xffff0000u); }
__device__ __forceinline__ float bflo(unsigned int w) { return __uint_as_float(w << 16); }

// ---------------- K1: u_hat = W.x, store bf16 ----------------
// grid: M * 28 (p-tiles of 7), 256 threads. thread: bq=t>>5 (4 b's), doq=t&31 (10 j's)
__global__ __launch_bounds__(256)
void caps_u(const float* __restrict__ x, const float* __restrict__ W,
            unsigned short* __restrict__ uh)
{
    __shared__ float x_lds[7 * 260];   // [p][b*8 + h*4], stride 260 breaks bank aliasing
    const int m  = blockIdx.x / 28;
    const int pt = blockIdx.x % 28;
    const int p0 = pt * 7;
    const int t  = threadIdx.x;
    const int bq = t >> 5, doq = t & 31;

    for (int f = t; f < 7 * 32 * 2; f += 256) {
        int b = f / 14, r = f % 14, p = r >> 1, h = r & 1;
        *(float4*)(x_lds + p * 260 + b * 8 + h * 4) =
            *(const float4*)(x + (((size_t)b * M_ + m) * P_ + p0 + p) * I_ + h * 4);
    }
    __syncthreads();

    for (int pl = 0; pl < 7; pl++) {
        const float* wp = W + (size_t)(m * P_ + p0 + pl) * DO_ * I_;
        float xr[4][8];
        #pragma unroll
        for (int bb = 0; bb < 4; bb++) {
            float4 a0 = *(const float4*)(x_lds + pl * 260 + (bq * 4 + bb) * 8);
            float4 a1 = *(const float4*)(x_lds + pl * 260 + (bq * 4 + bb) * 8 + 4);
            xr[bb][0]=a0.x; xr[bb][1]=a0.y; xr[bb][2]=a0.z; xr[bb][3]=a0.w;
            xr[bb][4]=a1.x; xr[bb][5]=a1.y; xr[bb][6]=a1.z; xr[bb][7]=a1.w;
        }
        unsigned short* uhp[4];
        #pragma unroll
        for (int bb = 0; bb < 4; bb++)
            uhp[bb] = uh + (((size_t)(bq * 4 + bb) * M_ + m) * P_ + p0 + pl) * DO_ + doq;
        #pragma unroll
        for (int j = 0; j < 10; j++) {
            const float4* w4 = (const float4*)(wp + (doq + 32 * j) * I_);
            float4 w0 = w4[0], w1 = w4[1];
            #pragma unroll
            for (int bb = 0; bb < 4; bb++) {
                float s = w0.x * xr[bb][0];
                s = fmaf(w0.y, xr[bb][1], s);
                s = fmaf(w0.z, xr[bb][2], s);
                s = fmaf(w0.w, xr[bb][3], s);
                s = fmaf(w1.x, xr[bb][4], s);
                s = fmaf(w1.y, xr[bb][5], s);
                s = fmaf(w1.z, xr[bb][6], s);
                s = fmaf(w1.w, xr[bb][7], s);
                uhp[bb][32 * j] = f2bf(s);
            }
        }
    }
}

// ---------------- route: one block per (b,m) row of u_hat ----------------
// MODE 0: s1 partial (uniform c, unscaled sum; /PD applied in squash)
// MODE 1: online-softmax s partial (blog = u.v)
// MODE 2: same + c_maps + features outputs
// thread t: d = t%20, chunk k = t/20 (16 chunks over P), owns full o in regs.
template<int MODE>
__global__ __launch_bounds__(320)
void route_k(const unsigned short* __restrict__ uh, const float* __restrict__ vin,
             float* __restrict__ pbm, float* __restrict__ out)
{
    extern __shared__ float sm[];
    float* accL  = sm;               // [320*17]
    float* red   = sm + 320 * 17;    // [16]
    float* blogL = red + 16;         // [3920] (MODE2)
    float* usqL  = blogL + 3920;     // [3920] (MODE2)

    const int blk = blockIdx.x;      // b*32 + m
    const int t = threadIdx.x;
    const int d = t % 20;
    const int k = t / 20;
    const int pstart = k * 12 + (k < 4 ? k : 4);
    const int pcnt   = (k < 4) ? 13 : 12;
    const unsigned short* up = uh + (size_t)blk * ROW_;

    float vreg[16];
    if (MODE) {
        const float* vb = vin + (size_t)(blk >> 5) * DO_;
        #pragma unroll
        for (int o = 0; o < 16; o++) vreg[o] = vb[d * 16 + o];
    }
    float acc[16];
    #pragma unroll
    for (int o = 0; o < 16; o++) acc[o] = 0.f;
    float mloc = -1e30f, Z = 0.f;

    for (int pp = 0; pp < pcnt; pp++) {
        const int p = pstart + pp;
        const float4* a = (const float4*)(up + (size_t)p * DO_ + d * 16);
        float4 a0 = a[0], a1 = a[1];
        unsigned int ua[8];
        ua[0]=__float_as_uint(a0.x); ua[1]=__float_as_uint(a0.y);
        ua[2]=__float_as_uint(a0.z); ua[3]=__float_as_uint(a0.w);
        ua[4]=__float_as_uint(a1.x); ua[5]=__float_as_uint(a1.y);
        ua[6]=__float_as_uint(a1.z); ua[7]=__float_as_uint(a1.w);
        float u[16];
        #pragma unroll
        for (int q = 0; q < 8; q++) { u[2*q] = bflo(ua[q]); u[2*q+1] = bfhi(ua[q]); }

        if (MODE) {
            float bl = u[0] * vreg[0];
            #pragma unroll
            for (int o = 1; o < 16; o++) bl = fmaf(u[o], vreg[o], bl);
            if (MODE == 2) {
                float us = u[0] * u[0];
                #pragma unroll
                for (int o = 1; o < 16; o++) us = fmaf(u[o], u[o], us);
                blogL[p * D_ + d] = bl;
                usqL[p * D_ + d]  = us;
            }
            if (bl > mloc + 8.f) {           // defer-max rescale (T13)
                float r = __expf(mloc - bl);
                Z *= r;
                #pragma unroll
                for (int o = 0; o < 16; o++) acc[o] *= r;
                mloc = bl;
            }
            float e = __expf(bl - mloc);
            Z += e;
            #pragma unroll
            for (int o = 0; o < 16; o++) acc[o] = fmaf(e, u[o], acc[o]);
        } else {
            #pragma unroll
            for (int o = 0; o < 16; o++) acc[o] += u[o];
        }
    }

    float f = 1.f, iz = 1.f, mx = 0.f;
    if (MODE) {
        mx = mloc;
        #pragma unroll
        for (int msk = 1; msk < 64; msk <<= 1) mx = fmaxf(mx, __shfl_xor(mx, msk, 64));
        if ((t & 63) == 0) red[t >> 6] = mx;
        __syncthreads();
        mx = fmaxf(fmaxf(fmaxf(red[0], red[1]), fmaxf(red[2], red[3])), red[4]);
        f = __expf(mloc - mx);
        float zz = Z * f;
        #pragma unroll
        for (int msk = 1; msk < 64; msk <<= 1) zz += __shfl_xor(zz, msk, 64);
        if ((t & 63) == 0) red[8 + (t >> 6)] = zz;
        __syncthreads();
        iz = 1.f / (red[8] + red[9] + red[10] + red[11] + red[12]);
    }
    #pragma unroll
    for (int o = 0; o < 16; o++) accL[t * 17 + o] = acc[o] * f;
    __syncthreads();
    {
        const int dd = t >> 4, oo = t & 15;
        float s = 0.f;
        #pragma unroll
        for (int kk = 0; kk < 16; kk++) s += accL[(kk * 20 + dd) * 17 + oo];
        s *= iz;
        pbm[(size_t)blk * DO_ + t] = s;
        if (MODE == 2) out[FEAT_OFF + (size_t)blk * DO_ + t] = s * (1.f / 196.f);
    }
    if (MODE == 2) {
        for (int e = t; e < PD_; e += 320)
            out[CMAPS_OFF + (size_t)blk * PD_ + e] =
                __expf(blogL[e] - mx) * iz * sqrtf(usqL[e]);
    }
}

// ---------------- squash: per b, sum partials over m ----------------
// W 0: scale 1/PD, write v1. W 1: write vs = v1 + v2. W 2: write v to out.
template<int WH>
__global__ __launch_bounds__(320)
void sq2_k(const float* __restrict__ pbm, float* __restrict__ v1,
           float* __restrict__ vs, float* __restrict__ out)
{
    const int b = blockIdx.x, t = threadIdx.x;
    float s = 0.f;
    for (int mi = 0; mi < M_; mi++) s += pbm[((size_t)b * M_ + mi) * DO_ + t];
    if (WH == 0) s *= (1.f / PD_);
    float sq = s * s;
    #pragma unroll
    for (int msk = 1; msk < 16; msk <<= 1) sq += __shfl_xor(sq, msk, 16);
    float vr = (sq / (1.f + sq)) * s * rsqrtf(sq + 1e-9f);
    if (WH == 0) v1[(size_t)b * DO_ + t] = vr;
    if (WH == 1) vs[(size_t)b * DO_ + t] = v1[(size_t)b * DO_ + t] + vr;
    if (WH == 2) out[(size_t)b * DO_ + t] = vr;
}

extern "C" void kernel_launch(void* const* d_in, const int* in_sizes, int n_in,
                              void* d_out, int out_size, void* d_ws, size_t ws_size,
                              hipStream_t stream)
{
    const float* x = (const float*)d_in[0];
    const float* W = (const float*)d_in[1];
    float* out = (float*)d_out;

    unsigned short* uh = (unsigned short*)d_ws;
    // u_hat bf16: B*M*P*DO = 64,225,280 ushorts = 128,450,560 bytes
    float* fws = (float*)((char*)d_ws + (size_t)64225280 * 2);
    float* pbm = fws;                   // [B][M][DO] = 327,680 fl
    float* v1  = pbm + (size_t)B_ * M_ * DO_;
    float* vs  = v1 + (size_t)B_ * DO_;

    const size_t LDS_A = (320 * 17 + 16) * sizeof(float);
    const size_t LDS_B = LDS_A + 2 * PD_ * sizeof(float);

    caps_u<<<M_ * 28, 256, 0, stream>>>(x, W, uh);

    route_k<0><<<B_ * M_, 320, LDS_A, stream>>>(uh, v1, pbm, out);
    sq2_k<0><<<B_, 320, 0, stream>>>(pbm, v1, vs, out);

    route_k<1><<<B_ * M_, 320, LDS_A, stream>>>(uh, v1, pbm, out);
    sq2_k<1><<<B_, 320, 0, stream>>>(pbm, v1, vs, out);

    route_k<2><<<B_ * M_, 320, LDS_B, stream>>>(uh, vs, pbm, out);
    sq2_k<2><<<B_, 320, 0, stream>>>(pbm, v1, vs, out);
}